// Round 7
// baseline (324.187 us; speedup 1.0000x reference)
//
#include <hip/hip_runtime.h>

typedef float f32x4 __attribute__((ext_vector_type(4)));

#define B_  512
#define T_  64
#define N_  30
#define FIN 512
#define D_  256
#define C_  7
#define NN  900

// 8 waves = 2 K-halves (kq) x 2 row-groups (g) x 2 col-halves (cgrp).
// Row-groups OVERLAP: g0 = rows 0..15, g1 = rows 14..29 (no OOB, no masks).
// Lane: 8 rows x 4 cols x 256 K. acc = 8 x f32x4 = 32 VGPR (no spill).
// No LDS in the GEMM loop: real via wave-uniform broadcast loads (mult=c=2),
// W via coalesced loads (mult=g=2 -> 1 MB/block L2). LDS only for the
// xw combine + epilogue (~35.5 KB -> 4 blocks/CU).
__global__ __launch_bounds__(512, 4)
void digcn_fused(const float* __restrict__ real,
                 const float* __restrict__ gs,
                 const float* __restrict__ W,
                 const float* __restrict__ conv_bias,
                 const float* __restrict__ pool_w,
                 const float* __restrict__ pool_b,
                 const float* __restrict__ head_w,
                 const float* __restrict__ head_b,
                 float* __restrict__ out)
{
    __shared__ __align__(16) float xwS[N_ * D_];     // 30720 B
    __shared__ __align__(16) float adjS[32 * 32];    // 4096 B
    __shared__ float scoreS[4 * 32];
    __shared__ float sumS[32];
    __shared__ float logitS[8];

    const int tid  = threadIdx.x;
    const int b    = blockIdx.x;
    const int w    = tid >> 6;          // wave 0..7
    const int l    = tid & 63;
    const int kq   = w & 1;             // K-half: [kq*256, kq*256+256)
    const int g    = (w >> 1) & 1;      // row-group start g*14
    const int cgrp = w >> 2;            // col-half
    const int rh   = l >> 5;            // row sub-half
    const int r0   = g * 14 + rh * 8;   // 8 rows: r0..r0+7 (max 29)
    const int c0   = cgrp * 128 + (l & 31) * 4;

    const float* realb = real + (size_t)b * (N_ * FIN) + r0 * FIN + kq * 256;
    const float* gsb   = gs   + (size_t)b * (T_ * NN);
    const float* Wb    = W + (size_t)(kq * 256) * D_ + c0;

    f32x4 acc[8];
    #pragma unroll
    for (int rr = 0; rr < 8; ++rr) acc[rr] = (f32x4){0.f, 0.f, 0.f, 0.f};
    float adj0 = 0.f, adj1 = 0.f;

    // gs slice-0 prefetch
    float pg0 = gsb[tid];
    float pg1 = (tid + 512 < NN) ? gsb[tid + 512] : 0.f;

    // ---- main loop: 64 chunks x 4 k; 128 v_fma vs 14 VMEM, 0 DS, 0 barriers ----
    for (int it = 0; it < 64; ++it) {
        float ng0 = 0.f, ng1 = 0.f;
        if (it < 63) {
            ng0 = gsb[(it + 1) * NN + tid];
            if (tid + 512 < NN) ng1 = gsb[(it + 1) * NN + tid + 512];
        }
        const float* Wit = Wb + it * 4 * D_;
        f32x4 wv0 = *(const f32x4*)(Wit);
        f32x4 wv1 = *(const f32x4*)(Wit + D_);
        f32x4 wv2 = *(const f32x4*)(Wit + 2 * D_);
        f32x4 wv3 = *(const f32x4*)(Wit + 3 * D_);
        const float* rp = realb + it * 4;
        #pragma unroll
        for (int rr = 0; rr < 8; ++rr) {
            f32x4 rv = *(const f32x4*)(rp + rr * FIN);   // wave-uniform broadcast
            acc[rr] += wv0 * rv[0];
            acc[rr] += wv1 * rv[1];
            acc[rr] += wv2 * rv[2];
            acc[rr] += wv3 * rv[3];
        }
        adj0 += pg0; adj1 += pg1;
        pg0 = ng0;  pg1 = ng1;
    }

    // ---- adj mean + kq0 xw write (before barrier 1) ----
    {
        int i = tid / N_, j = tid - i * N_;              // tid < 900 always
        adjS[i * 32 + j] = adj0 * (1.f / (float)T_);
        int e = tid + 512;
        if (e < NN) {
            int i2 = e / N_, j2 = e - i2 * N_;
            adjS[i2 * 32 + j2] = adj1 * (1.f / (float)T_);
        }
        if (tid < 60) adjS[(tid >> 1) * 32 + 30 + (tid & 1)] = 0.f;  // zero pad cols
    }
    if (kq == 0) {
        // overlap rows 14,15 double-written with bit-identical values (same
        // instruction stream + same data) -> benign
        #pragma unroll
        for (int rr = 0; rr < 8; ++rr)
            *(f32x4*)(xwS + (r0 + rr) * D_ + c0) = acc[rr];
    }
    __syncthreads();
    if (kq == 1) {
        #pragma unroll
        for (int rr = 0; rr < 8; ++rr) {
            int row = r0 + rr;
            if (!(g == 1 && row < 16)) {                 // skip duplicate add on 14,15
                float* p = xwS + row * D_ + c0;
                *(f32x4*)p = *(const f32x4*)p + acc[rr];
            }
        }
    }
    __syncthreads();

    // ---- P3: agg = adj^T @ xw, ReLU, pool (threads 0..255, thread owns d) ----
    if (tid < D_) {
        float xcol[N_];
        #pragma unroll
        for (int i = 0; i < N_; ++i) xcol[i] = xwS[i * D_ + tid];   // lanes stride-1
        const float bias = conv_bias[tid];
        const float pw   = pool_w[tid];

        #pragma unroll
        for (int j0 = 0; j0 < N_ + 2; j0 += 4) {
            f32x4 agg = (f32x4){0.f, 0.f, 0.f, 0.f};
            #pragma unroll
            for (int i = 0; i < N_; ++i) {
                f32x4 a4 = *(const f32x4*)(adjS + i * 32 + j0);     // uniform broadcast
                agg += a4 * xcol[i];
            }
            #pragma unroll
            for (int c = 0; c < 4; ++c) {
                if (j0 + c < N_) {
                    float h = agg[c] + bias;
                    h = h > 0.f ? h : 0.f;
                    float v = h * pw;
                    #pragma unroll
                    for (int m = 32; m >= 1; m >>= 1) v += __shfl_xor(v, m, 64);
                    if (l == 0) scoreS[w * 32 + j0 + c] = v;
                }
            }
        }
    }
    __syncthreads();

    // ---- P4: combine waves, head matmul, softmax ----
    if (tid < N_)
        sumS[tid] = scoreS[tid] + scoreS[32 + tid] + scoreS[64 + tid] + scoreS[96 + tid]
                  + pool_b[0];
    __syncthreads();
    if (tid < C_) {
        float lg = head_b[tid];
        #pragma unroll
        for (int j = 0; j < N_; ++j) lg += sumS[j] * head_w[tid * N_ + j];
        logitS[tid] = lg;
    }
    __syncthreads();
    if (tid < C_) {
        float m = logitS[0];
        #pragma unroll
        for (int c = 1; c < C_; ++c) m = fmaxf(m, logitS[c]);
        float s = 0.f;
        #pragma unroll
        for (int c = 0; c < C_; ++c) s += expf(logitS[c] - m);
        out[b * C_ + tid] = expf(logitS[tid] - m) / s;
    }
}

extern "C" void kernel_launch(void* const* d_in, const int* in_sizes, int n_in,
                              void* d_out, int out_size, void* d_ws, size_t ws_size,
                              hipStream_t stream) {
    const float* real      = (const float*)d_in[0];
    // d_in[1] (imag) is unused by the forward pass
    const float* gs        = (const float*)d_in[2];
    const float* W         = (const float*)d_in[3];
    const float* conv_bias = (const float*)d_in[4];
    const float* pool_w    = (const float*)d_in[5];
    const float* pool_b    = (const float*)d_in[6];
    const float* head_w    = (const float*)d_in[7];
    const float* head_b    = (const float*)d_in[8];
    float* outp            = (float*)d_out;

    digcn_fused<<<dim3(B_), dim3(512), 0, stream>>>(
        real, gs, W, conv_bias, pool_w, pool_b, head_w, head_b, outp);
}